// Round 6
// baseline (554.809 us; speedup 1.0000x reference)
//
#include <hip/hip_runtime.h>
#include <hip/hip_bf16.h>
#include <math.h>

#define EPS 1e-5f

typedef __hip_bfloat16 bf16;
typedef short short8 __attribute__((ext_vector_type(8)));
typedef float float4v __attribute__((ext_vector_type(4)));

__device__ __forceinline__ float toF(float v) { return v; }
__device__ __forceinline__ float toF(bf16 v) { return __bfloat162float(v); }
__device__ __forceinline__ void stF(float* p, float v) { *p = v; }
__device__ __forceinline__ void stF(bf16* p, float v) { *p = __float2bfloat16(v); }
__device__ __forceinline__ short f2bs(float v) {
    bf16 b = __float2bfloat16(v);
    return *reinterpret_cast<short*>(&b);
}
__device__ __forceinline__ float bs2f(short s) {
    unsigned u = ((unsigned)(unsigned short)s) << 16;
    return __uint_as_float(u);
}

// ---------------- block reduction (blockDim.x == 256) ----------------
__device__ __forceinline__ float block_reduce_sum(float v) {
    __shared__ float s[256];
    int t = threadIdx.x;
    s[t] = v;
    __syncthreads();
    #pragma unroll
    for (int st = 128; st > 0; st >>= 1) {
        if (t < st) s[t] += s[t + st];
        __syncthreads();
    }
    float r = s[0];
    __syncthreads();
    return r;
}

// ---------------- ternarize -> bf16 {-1,0,+1} + fp32 alpha ----------------
__global__ void ternarize_kernel(const float* __restrict__ w, short* __restrict__ wt,
                                 float* __restrict__ alpha, int K) {
    int f = blockIdx.x;
    const float* wf = w + (size_t)f * K;
    short* wtf = wt + (size_t)f * K;

    float s = 0.f;
    for (int i = threadIdx.x; i < K; i += blockDim.x) s += fabsf(wf[i]);
    float total = block_reduce_sum(s);
    float delta = 0.7f * total / (float)K;

    float sm = 0.f, cm = 0.f;
    for (int i = threadIdx.x; i < K; i += blockDim.x) {
        float a = fabsf(wf[i]);
        if (a > delta) { sm += a; cm += 1.f; }
    }
    sm = block_reduce_sum(sm);
    cm = block_reduce_sum(cm);
    if (threadIdx.x == 0) alpha[f] = sm / (cm + 1e-8f);

    for (int i = threadIdx.x; i < K; i += blockDim.x) {
        float v = wf[i];
        float a = fabsf(v);
        wtf[i] = (a > delta) ? ((v > 0.f) ? (short)0x3F80 : (short)0xBF80) : (short)0;
    }
}

// ---------------- fold bn1 scale into w1t + compute bias1 = w1t . shift1 ----------------
__global__ void foldbias_kernel(const short* __restrict__ wt, const float* __restrict__ scale,
                                const float* __restrict__ shift, short* __restrict__ wf,
                                float* __restrict__ bias, int K) {
    int f = blockIdx.x;
    float s = 0.f;
    for (int k = threadIdx.x; k < K; k += blockDim.x) {
        float tv = bs2f(wt[(size_t)f * K + k]);
        wf[(size_t)f * K + k] = f2bs(tv * scale[k]);
        s += tv * shift[k];
    }
    s = block_reduce_sum(s);
    if (threadIdx.x == 0) bias[f] = s;
}

// ---------------- fp32 -> bf16 cast ----------------
__global__ void f2bf_kernel(const float* __restrict__ in, short* __restrict__ out, int n) {
    int i = blockIdx.x * blockDim.x + threadIdx.x;
    if (i < n) out[i] = f2bs(in[i]);
}

// ---------------- BN stats phase A: vectorized partial sums + atomics ----------------
template <typename T, int VEC>
__global__ __launch_bounds__(256) void bn_sum_kernel(
    const T* __restrict__ src, float* __restrict__ sum, float* __restrict__ sq,
    int C, int spatial, int N, int splits) {
    int c = blockIdx.x;
    int vpc = spatial / VEC;          // vectors per (n,c) chunk
    int total = N * vpc;
    float s = 0.f, s2 = 0.f;
    for (int v = blockIdx.y * 256 + threadIdx.x; v < total; v += splits * 256) {
        int n = v / vpc;
        int i = v - n * vpc;
        const T* p = src + ((size_t)n * C + c) * spatial + i * VEC;
        float vals[VEC];
        if (sizeof(T) == 4) {
            float4 q = *(const float4*)p;
            vals[0] = q.x; vals[1] = q.y; vals[2] = q.z; vals[3] = q.w;
        } else {
            short tmp[VEC];
            if (VEC == 8) *(int4*)tmp = *(const int4*)p;
            else          *(int2*)tmp = *(const int2*)p;
            #pragma unroll
            for (int k = 0; k < VEC; k++) vals[k] = bs2f(tmp[k]);
        }
        #pragma unroll
        for (int k = 0; k < VEC; k++) { s += vals[k]; s2 += vals[k] * vals[k]; }
    }
    s = block_reduce_sum(s);
    s2 = block_reduce_sum(s2);
    if (threadIdx.x == 0) {
        atomicAdd(&sum[c], s);
        atomicAdd(&sq[c], s2);
    }
}

// ---------------- BN stats phase B: finalize scale/shift ----------------
__global__ void bn_finalize_kernel(const float* __restrict__ sum, const float* __restrict__ sq,
                                   const float* __restrict__ g, const float* __restrict__ b,
                                   float* __restrict__ scale, float* __restrict__ shift,
                                   int C, float cnt) {
    int c = blockIdx.x * blockDim.x + threadIdx.x;
    if (c >= C) return;
    float mean = sum[c] / cnt;
    float var = fmaxf(sq[c] / cnt - mean * mean, 0.f);
    float r = rsqrtf(var + EPS);
    float sc = g[c] * r;
    scale[c] = sc;
    shift[c] = b[c] - mean * sc;
}

// ---------------- fused stats + raw transpose (VMEM-wide version) ----------------
__global__ __launch_bounds__(256) void stats_transpose_kernel(
    const float* __restrict__ in, short* __restrict__ Bt,
    float* __restrict__ sum, float* __restrict__ sq, int C, int SP) {
    __shared__ short tile[64][66];
    __shared__ float rs[4][64], rq[4][64];
    int n = blockIdx.z;
    int ci0 = blockIdx.y * 64;
    int p0 = blockIdx.x * 64;
    int t = threadIdx.x;
    int tx = t & 63;
    int ty4 = t >> 6;  // 0..3

    // phase 1: float4 loads along p
    {
        int p4 = t & 15;
        int cib = t >> 4;
        int p = p0 + p4 * 4;
        bool pok = (p + 3) < SP;          // SP%4==0 -> all-or-none per float4
        #pragma unroll
        for (int it = 0; it < 4; it++) {
            int ci = cib + it * 16;
            float4 q;
            if (pok) q = *(const float4*)(in + ((size_t)n * C + ci0 + ci) * SP + p);
            else     q = make_float4(0.f, 0.f, 0.f, 0.f);
            tile[p4 * 4 + 0][ci] = f2bs(q.x);
            tile[p4 * 4 + 1][ci] = f2bs(q.y);
            tile[p4 * 4 + 2][ci] = f2bs(q.z);
            tile[p4 * 4 + 3][ci] = f2bs(q.w);
        }
    }
    __syncthreads();

    // phase 2a: int4 stores (8 shorts/lane)
    {
        int seg = t & 7;
        #pragma unroll
        for (int it = 0; it < 2; it++) {
            int pl = (t >> 3) + it * 32;
            int pw = p0 + pl;
            if (pw < SP) {
                short v[8];
                #pragma unroll
                for (int u = 0; u < 8; u++) v[u] = tile[pl][seg * 8 + u];
                *(int4*)(Bt + ((size_t)n * SP + pw) * C + ci0 + seg * 8) = *(int4*)v;
            }
        }
    }

    // phase 2b: per-channel stats from LDS
    float s = 0.f, s2 = 0.f;
    #pragma unroll
    for (int r = 0; r < 16; r++) {
        int pl = ty4 + r * 4;
        int pw = p0 + pl;
        if (pw < SP) {
            float v = bs2f(tile[pl][tx]);
            s += v; s2 += v * v;
        }
    }
    rs[ty4][tx] = s; rq[ty4][tx] = s2;
    __syncthreads();
    if (ty4 == 0) {
        float ts = rs[0][tx] + rs[1][tx] + rs[2][tx] + rs[3][tx];
        float tq = rq[0][tx] + rq[1][tx] + rq[2][tx] + rq[3][tx];
        atomicAdd(&sum[ci0 + tx], ts);
        atomicAdd(&sq[ci0 + tx], tq);
    }
}

// ---------------- affine transpose (bf16, VMEM-wide): h2 -> B3t ----------------
__global__ __launch_bounds__(256) void affine_transpose_bf16_kernel(
    const bf16* __restrict__ in, const float* __restrict__ scale,
    const float* __restrict__ shift, short* __restrict__ Bt,
    int C, int SP) {
    __shared__ short tile[64][66];
    int n = blockIdx.z;
    int ci0 = blockIdx.y * 64;
    int p0 = blockIdx.x * 64;
    int t = threadIdx.x;

    {
        int p4 = t & 15;
        int cib = t >> 4;
        int p = p0 + p4 * 4;
        bool pok = (p + 3) < SP;          // SP%4==0
        #pragma unroll
        for (int it = 0; it < 4; it++) {
            int ci = cib + it * 16;
            short v[4] = {0, 0, 0, 0};
            if (pok) *(int2*)v = *(const int2*)(in + ((size_t)n * C + ci0 + ci) * SP + p);
            float sc = scale[ci0 + ci], sh = shift[ci0 + ci];
            #pragma unroll
            for (int j = 0; j < 4; j++)
                tile[p4 * 4 + j][ci] = f2bs(bs2f(v[j]) * sc + sh);
        }
    }
    __syncthreads();

    {
        int seg = t & 7;
        #pragma unroll
        for (int it = 0; it < 2; it++) {
            int pl = (t >> 3) + it * 32;
            int pw = p0 + pl;
            if (pw < SP) {
                short v[8];
                #pragma unroll
                for (int u = 0; u < 8; u++) v[u] = tile[pl][seg * 8 + u];
                *(int4*)(Bt + ((size_t)n * SP + pw) * C + ci0 + seg * 8) = *(int4*)v;
            }
        }
    }
}

// ---------------- LDS-tiled im2col + affine for conv2 (3x3 s2 p1) ----------------
__global__ __launch_bounds__(256) void im2col_tiled_kernel(
    const bf16* __restrict__ h1, const float* __restrict__ scale,
    const float* __restrict__ shift, short* __restrict__ B2t) {
    __shared__ short tile[16][784];   // 25 KB
    int cb = blockIdx.x;              // 0..15 (16-channel slab)
    int n  = blockIdx.y;              // 0..63
    int ci0 = cb * 16;
    int t = threadIdx.x;

    for (int v = t; v < 16 * 98; v += 256) {
        int ci = v / 98;
        int i8 = (v - ci * 98) * 8;
        short tmp[8];
        *(int4*)tmp = *(const int4*)(h1 + ((size_t)n * 256 + ci0 + ci) * 784 + i8);
        float sc = scale[ci0 + ci], sh = shift[ci0 + ci];
        short ov[8];
        #pragma unroll
        for (int k = 0; k < 8; k++) ov[k] = f2bs(bs2f(tmp[k]) * sc + sh);
        *(int4*)&tile[ci][i8] = *(int4*)ov;
    }
    __syncthreads();

    for (int w = t; w < 196 * 18; w += 256) {
        int p = w / 18, seg = w - p * 18;
        int oh = p / 14, ow = p - oh * 14;
        int kbase = seg * 8;
        short vals[8];
        #pragma unroll
        for (int u = 0; u < 8; u++) {
            int kk = kbase + u;
            int ci_l = kk / 9;
            int rr = kk - ci_l * 9;
            int kh = rr / 3, kw = rr - kh * 3;
            int ih = 2 * oh - 1 + kh;
            int iw = 2 * ow - 1 + kw;
            vals[u] = ((unsigned)ih < 28u && (unsigned)iw < 28u)
                          ? tile[ci_l][ih * 28 + iw] : (short)0;
        }
        *(int4*)(B2t + ((size_t)(n * 196 + p)) * 2304 + ci0 * 9 + kbase) = *(int4*)vals;
    }
}

// ---------------- MFMA GEMM (BMxBN tile, BK=32, 4 waves, 16x16x32) ----------------
// Round-3 loop structure (validated 441.8us): loads at loop top, BKP=32, no
// cross-iteration register carry. BKP=40 pad and reg-prefetch REVERTED (r4: bank
// conflicts 1.8M->3.2M, MfmaUtil 7.8->5.6%, +100us — both falsified by counters).
// FUSE: epilogue adds scv*fscale[m]+fshift[m]. HAS_BIAS: folded-BN bias (GEMM1).
// BREMAP: B rows are a stride-2 subsample of 28x28 grids (GEMM4 reads raw B1t).
template <int BM, int BN, int SP, typename TOut, bool HAS_ALPHA, bool FUSE, bool HAS_BIAS, bool BREMAP>
__global__ __launch_bounds__(256) void gemm_kernel(
    const short* __restrict__ A, const short* __restrict__ Bt,
    const float* __restrict__ alpha, TOut* __restrict__ out,
    int M, int K,
    const bf16* __restrict__ scv, const float* __restrict__ fscale,
    const float* __restrict__ fshift, const float* __restrict__ bias) {
    constexpr int BKP = 32;
    constexpr int WM = BM / 2, WN = BN / 2;       // per-wave output (2x2 wave grid)
    constexpr int MI = WM / 16, NJ = WN / 16;
    constexpr int RA = BM / 64, RB = BN / 64;     // staging rows-per-thread
    __shared__ short As[BM * BKP];
    __shared__ short Bs[BN * BKP];
    int t = threadIdx.x;
    int c0 = blockIdx.x * BN;
    int m0 = blockIdx.y * BM;
    int w = t >> 6, l = t & 63;
    int wm = (w >> 1) * WM, wn = (w & 1) * WN;

    int r0 = t >> 2;          // 0..63
    int kg = (t & 3) * 8;     // 0,8,16,24

    // B row remap (hoisted: independent of k)
    size_t rowB[RB];
    #pragma unroll
    for (int rr = 0; rr < RB; rr++) {
        int c = c0 + r0 + rr * 64;
        if (BREMAP) {
            int nn = c / 196, pp = c - nn * 196;
            int oh = pp / 14, ow = pp - oh * 14;
            rowB[rr] = (size_t)nn * 784 + oh * 56 + ow * 2;
        } else {
            rowB[rr] = c;
        }
    }

    float4v acc[MI][NJ];
    #pragma unroll
    for (int i = 0; i < MI; i++)
        #pragma unroll
        for (int j = 0; j < NJ; j++) acc[i][j] = (float4v)0.f;

    int lm = (l >> 4);
    int lc = l & 15;

    for (int k0 = 0; k0 < K; k0 += 32) {
        int4 av[RA], bv[RB];
        #pragma unroll
        for (int rr = 0; rr < RA; rr++)
            av[rr] = *(const int4*)(A + (size_t)(m0 + r0 + rr * 64) * K + k0 + kg);
        #pragma unroll
        for (int rr = 0; rr < RB; rr++)
            bv[rr] = *(const int4*)(Bt + rowB[rr] * K + k0 + kg);
        __syncthreads();
        #pragma unroll
        for (int rr = 0; rr < RA; rr++)
            *(int4*)&As[(r0 + rr * 64) * BKP + kg] = av[rr];
        #pragma unroll
        for (int rr = 0; rr < RB; rr++)
            *(int4*)&Bs[(r0 + rr * 64) * BKP + kg] = bv[rr];
        __syncthreads();

        short8 af[MI], bfr[NJ];
        #pragma unroll
        for (int i = 0; i < MI; i++)
            af[i] = *(const short8*)&As[(wm + i * 16 + lc) * BKP + lm * 8];
        #pragma unroll
        for (int j = 0; j < NJ; j++)
            bfr[j] = *(const short8*)&Bs[(wn + j * 16 + lc) * BKP + lm * 8];
        #pragma unroll
        for (int i = 0; i < MI; i++)
            #pragma unroll
            for (int j = 0; j < NJ; j++)
                acc[i][j] = __builtin_amdgcn_mfma_f32_16x16x32_bf16(af[i], bfr[j], acc[i][j], 0, 0, 0);
    }

    #pragma unroll
    for (int i = 0; i < MI; i++) {
        #pragma unroll
        for (int r = 0; r < 4; r++) {
            int m = m0 + wm + i * 16 + lm * 4 + r;
            float a = HAS_ALPHA ? alpha[m] : 1.f;
            float bia = HAS_BIAS ? bias[m] : 0.f;
            float fsc = FUSE ? fscale[m] : 0.f;
            float fsh = FUSE ? fshift[m] : 0.f;
            #pragma unroll
            for (int j = 0; j < NJ; j++) {
                int c = c0 + wn + j * 16 + lc;
                int n = c / SP;
                int p = c - n * SP;
                size_t idx = ((size_t)n * M + m) * SP + p;
                float v = acc[i][j][r];
                if (HAS_BIAS) v += bia;
                if (HAS_ALPHA) v *= a;
                if (FUSE) v += toF(scv[idx]) * fsc + fsh;
                stF(&out[idx], v);
            }
        }
    }
}

extern "C" void kernel_launch(void* const* d_in, const int* in_sizes, int n_in,
                              void* d_out, int out_size, void* d_ws, size_t ws_size,
                              hipStream_t stream) {
    const float* x      = (const float*)d_in[0];   // (64,512,28,28)
    const float* bn1_g  = (const float*)d_in[1];
    const float* bn1_b  = (const float*)d_in[2];
    const float* w1     = (const float*)d_in[3];   // (256,512,1,1)
    const float* bn2_g  = (const float*)d_in[4];
    const float* bn2_b  = (const float*)d_in[5];
    const float* w2     = (const float*)d_in[6];   // (256,256,3,3)
    const float* bn3_g  = (const float*)d_in[7];
    const float* bn3_b  = (const float*)d_in[8];
    const float* w3     = (const float*)d_in[9];   // (1024,256,1,1)
    const float* ds_w   = (const float*)d_in[10];  // (1024,512,1,1) NOT ternarized
    const float* dbn_g  = (const float*)d_in[11];
    const float* dbn_b  = (const float*)d_in[12];
    float* out = (float*)d_out;

    const int N = 64, C1 = 512, C2 = 256, C3 = 1024;
    const int SP1 = 784, SP2 = 196;
    const int NT1 = N * SP1;   // 50176
    const int NT2 = N * SP2;   // 12544

    // ---- workspace layout ----
    char* wsb = (char*)d_ws;
    size_t off = 0;
    auto alloc = [&](size_t bytes) { char* p = wsb + off; off += (bytes + 255) & ~(size_t)255; return p; };

    char* pool = alloc((size_t)NT2 * 2304 * 2);   // 57.8 MB: B1t (51.4) / B2t (57.8) / B3t (6.4) time-share
    short* B1t = (short*)pool;                    // raw bf16(x)^T; live until GEMM4
    short* B2t = (short*)pool;                    // created by im2col AFTER GEMM4
    short* B3t = (short*)pool;                    // created after B2t is dead
    bf16*  sc  = (bf16*)alloc((size_t)N * C3 * SP2 * 2);  // 25.7 MB, own region (lives across im2col)

    bf16* h1 = (bf16*)alloc((size_t)N * C2 * SP1 * 2);
    bf16* h2 = (bf16*)alloc((size_t)N * C2 * SP2 * 2);
    short* w1t  = (short*)alloc((size_t)C2 * C1 * 2);
    short* w1f  = (short*)alloc((size_t)C2 * C1 * 2);   // scale-folded w1
    short* w2t  = (short*)alloc((size_t)C2 * C2 * 9 * 2);
    short* w3t  = (short*)alloc((size_t)C3 * C2 * 2);
    short* dswb = (short*)alloc((size_t)C3 * C1 * 2);
    float* alpha1 = (float*)alloc(C2 * 4);
    float* alpha2 = (float*)alloc(C2 * 4);
    float* alpha3 = (float*)alloc(C3 * 4);
    float* bias1  = (float*)alloc(C2 * 4);
    float* scale1 = (float*)alloc(C1 * 4);
    float* shift1 = (float*)alloc(C1 * 4);
    float* scale2 = (float*)alloc(C2 * 4);
    float* shift2 = (float*)alloc(C2 * 4);
    float* scale3 = (float*)alloc(C2 * 4);
    float* shift3 = (float*)alloc(C2 * 4);
    float* scaled = (float*)alloc(C3 * 4);
    float* shiftd = (float*)alloc(C3 * 4);
    float* acc_base = (float*)alloc((size_t)(C1 + C2 + C2 + C3) * 2 * 4);
    float* sum1 = acc_base;            float* sq1 = sum1 + C1;
    float* sum2 = sq1 + C1;            float* sq2 = sum2 + C2;
    float* sum3 = sq2 + C2;            float* sq3 = sum3 + C2;
    float* sumd = sq3 + C2;            float* sqd = sumd + C3;
    (void)ws_size; (void)in_sizes; (void)n_in; (void)out_size;

    // 0) zero BN accumulators
    hipMemsetAsync(acc_base, 0, (size_t)(C1 + C2 + C2 + C3) * 2 * 4, stream);

    // 1) weights
    ternarize_kernel<<<C2, 256, 0, stream>>>(w1, w1t, alpha1, C1);
    ternarize_kernel<<<C2, 256, 0, stream>>>(w2, w2t, alpha2, C2 * 9);
    ternarize_kernel<<<C3, 256, 0, stream>>>(w3, w3t, alpha3, C2);
    f2bf_kernel<<<(C3 * C1 + 255) / 256, 256, 0, stream>>>(ds_w, dswb, C3 * C1);

    // 2) single pass over x: B1t = raw bf16(x)^T + bn1 stats; then finalize + fold into w1
    {
        dim3 grid((SP1 + 63) / 64, C1 / 64, N);
        stats_transpose_kernel<<<grid, 256, 0, stream>>>(x, B1t, sum1, sq1, C1, SP1);
    }
    bn_finalize_kernel<<<(C1 + 255) / 256, 256, 0, stream>>>(sum1, sq1, bn1_g, bn1_b,
                                                             scale1, shift1, C1, (float)(N * SP1));
    foldbias_kernel<<<C2, 256, 0, stream>>>(w1t, scale1, shift1, w1f, bias1, C1);

    // 3) GEMM1: h1 = alpha1 * (w1f . B1t^T + bias1)   M=256 K=512 SP=784
    gemm_kernel<128, 128, 784, bf16, true, false, true, false>
        <<<dim3(NT1 / 128, C2 / 128), 256, 0, stream>>>(
        w1f, B1t, alpha1, h1, C2, C1, nullptr, nullptr, nullptr, bias1);

    // 4) shortcut GEMM4 straight from raw B1t (stride-2 row remap): sc = dswb . B1t_s2^T
    //    M=1024 K=512 SP=196 — must run BEFORE im2col overwrites the pool
    gemm_kernel<128, 128, 196, bf16, false, false, false, true>
        <<<dim3(NT2 / 128, C3 / 128), 256, 0, stream>>>(
        dswb, B1t, nullptr, sc, C3, C1, nullptr, nullptr, nullptr, nullptr);

    // 5) ds bn stats on sc
    bn_sum_kernel<bf16, 4><<<dim3(C3, 4), 256, 0, stream>>>(sc, sumd, sqd, C3, SP2, N, 4);
    bn_finalize_kernel<<<(C3 + 255) / 256, 256, 0, stream>>>(sumd, sqd, dbn_g, dbn_b,
                                                             scaled, shiftd, C3, (float)(N * SP2));

    // 6) bn2 stats + LDS-tiled im2col (B2t overwrites pool — B1t dead now)
    bn_sum_kernel<bf16, 8><<<dim3(C2, 8), 256, 0, stream>>>(h1, sum2, sq2, C2, SP1, N, 8);
    bn_finalize_kernel<<<(C2 + 255) / 256, 256, 0, stream>>>(sum2, sq2, bn2_g, bn2_b,
                                                             scale2, shift2, C2, (float)(N * SP1));
    im2col_tiled_kernel<<<dim3(16, 64), 256, 0, stream>>>(h1, scale2, shift2, B2t);

    // 7) GEMM2: h2 = alpha2 * (w2t . B2t^T)   M=256 K=2304 SP=196
    //    64x64 tiles -> 784 blocks (validated in r4: left the top-5)
    gemm_kernel<64, 64, 196, bf16, true, false, false, false>
        <<<dim3(NT2 / 64, C2 / 64), 256, 0, stream>>>(
        w2t, B2t, alpha2, h2, C2, C2 * 9, nullptr, nullptr, nullptr, nullptr);

    // 8) bn3 stats + B3t = bn3(h2)^T (vectorized transpose)
    bn_sum_kernel<bf16, 4><<<dim3(C2, 4), 256, 0, stream>>>(h2, sum3, sq3, C2, SP2, N, 4);
    bn_finalize_kernel<<<(C2 + 255) / 256, 256, 0, stream>>>(sum3, sq3, bn3_g, bn3_b,
                                                             scale3, shift3, C2, (float)(N * SP2));
    {
        dim3 grid((SP2 + 63) / 64, C2 / 64, N);
        affine_transpose_bf16_kernel<<<grid, 256, 0, stream>>>(
            h2, scale3, shift3, B3t, C2, SP2);
    }

    // 9) GEMM3 with fused residual: out = alpha3*(w3t . B3t^T) + sc*scaled + shiftd
    gemm_kernel<128, 128, 196, float, true, true, false, false>
        <<<dim3(NT2 / 128, C3 / 128), 256, 0, stream>>>(
        w3t, B3t, alpha3, out, C3, C2, sc, scaled, shiftd, nullptr);
}

// Round 7
// 435.667 us; speedup vs baseline: 1.2735x; 1.2735x over previous
//
#include <hip/hip_runtime.h>
#include <hip/hip_bf16.h>
#include <math.h>

#define EPS 1e-5f

typedef __hip_bfloat16 bf16;
typedef short short8 __attribute__((ext_vector_type(8)));
typedef float float4v __attribute__((ext_vector_type(4)));

__device__ __forceinline__ float toF(float v) { return v; }
__device__ __forceinline__ float toF(bf16 v) { return __bfloat162float(v); }
__device__ __forceinline__ void stF(float* p, float v) { *p = v; }
__device__ __forceinline__ void stF(bf16* p, float v) { *p = __float2bfloat16(v); }
__device__ __forceinline__ short f2bs(float v) {
    bf16 b = __float2bfloat16(v);
    return *reinterpret_cast<short*>(&b);
}
__device__ __forceinline__ float bs2f(short s) {
    unsigned u = ((unsigned)(unsigned short)s) << 16;
    return __uint_as_float(u);
}

// ---------------- block reduction (blockDim.x == 256) ----------------
__device__ __forceinline__ float block_reduce_sum(float v) {
    __shared__ float s[256];
    int t = threadIdx.x;
    s[t] = v;
    __syncthreads();
    #pragma unroll
    for (int st = 128; st > 0; st >>= 1) {
        if (t < st) s[t] += s[t + st];
        __syncthreads();
    }
    float r = s[0];
    __syncthreads();
    return r;
}

// ---------------- ternarize -> bf16 {-1,0,+1} + fp32 alpha ----------------
__global__ void ternarize_kernel(const float* __restrict__ w, short* __restrict__ wt,
                                 float* __restrict__ alpha, int K) {
    int f = blockIdx.x;
    const float* wf = w + (size_t)f * K;
    short* wtf = wt + (size_t)f * K;

    float s = 0.f;
    for (int i = threadIdx.x; i < K; i += blockDim.x) s += fabsf(wf[i]);
    float total = block_reduce_sum(s);
    float delta = 0.7f * total / (float)K;

    float sm = 0.f, cm = 0.f;
    for (int i = threadIdx.x; i < K; i += blockDim.x) {
        float a = fabsf(wf[i]);
        if (a > delta) { sm += a; cm += 1.f; }
    }
    sm = block_reduce_sum(sm);
    cm = block_reduce_sum(cm);
    if (threadIdx.x == 0) alpha[f] = sm / (cm + 1e-8f);

    for (int i = threadIdx.x; i < K; i += blockDim.x) {
        float v = wf[i];
        float a = fabsf(v);
        wtf[i] = (a > delta) ? ((v > 0.f) ? (short)0x3F80 : (short)0xBF80) : (short)0;
    }
}

// ---------------- fold bn1 scale into w1t + compute bias1 = w1t . shift1 ----------------
__global__ void foldbias_kernel(const short* __restrict__ wt, const float* __restrict__ scale,
                                const float* __restrict__ shift, short* __restrict__ wf,
                                float* __restrict__ bias, int K) {
    int f = blockIdx.x;
    float s = 0.f;
    for (int k = threadIdx.x; k < K; k += blockDim.x) {
        float tv = bs2f(wt[(size_t)f * K + k]);
        wf[(size_t)f * K + k] = f2bs(tv * scale[k]);
        s += tv * shift[k];
    }
    s = block_reduce_sum(s);
    if (threadIdx.x == 0) bias[f] = s;
}

// ---------------- fp32 -> bf16 cast ----------------
__global__ void f2bf_kernel(const float* __restrict__ in, short* __restrict__ out, int n) {
    int i = blockIdx.x * blockDim.x + threadIdx.x;
    if (i < n) out[i] = f2bs(in[i]);
}

// ---------------- BN stats phase A: vectorized partial sums + atomics ----------------
template <typename T, int VEC>
__global__ __launch_bounds__(256) void bn_sum_kernel(
    const T* __restrict__ src, float* __restrict__ sum, float* __restrict__ sq,
    int C, int spatial, int N, int splits) {
    int c = blockIdx.x;
    int vpc = spatial / VEC;          // vectors per (n,c) chunk
    int total = N * vpc;
    float s = 0.f, s2 = 0.f;
    for (int v = blockIdx.y * 256 + threadIdx.x; v < total; v += splits * 256) {
        int n = v / vpc;
        int i = v - n * vpc;
        const T* p = src + ((size_t)n * C + c) * spatial + i * VEC;
        float vals[VEC];
        if (sizeof(T) == 4) {
            float4 q = *(const float4*)p;
            vals[0] = q.x; vals[1] = q.y; vals[2] = q.z; vals[3] = q.w;
        } else {
            short tmp[VEC];
            if (VEC == 8) *(int4*)tmp = *(const int4*)p;
            else          *(int2*)tmp = *(const int2*)p;
            #pragma unroll
            for (int k = 0; k < VEC; k++) vals[k] = bs2f(tmp[k]);
        }
        #pragma unroll
        for (int k = 0; k < VEC; k++) { s += vals[k]; s2 += vals[k] * vals[k]; }
    }
    s = block_reduce_sum(s);
    s2 = block_reduce_sum(s2);
    if (threadIdx.x == 0) {
        atomicAdd(&sum[c], s);
        atomicAdd(&sq[c], s2);
    }
}

// ---------------- BN stats phase B: finalize scale/shift ----------------
__global__ void bn_finalize_kernel(const float* __restrict__ sum, const float* __restrict__ sq,
                                   const float* __restrict__ g, const float* __restrict__ b,
                                   float* __restrict__ scale, float* __restrict__ shift,
                                   int C, float cnt) {
    int c = blockIdx.x * blockDim.x + threadIdx.x;
    if (c >= C) return;
    float mean = sum[c] / cnt;
    float var = fmaxf(sq[c] / cnt - mean * mean, 0.f);
    float r = rsqrtf(var + EPS);
    float sc = g[c] * r;
    scale[c] = sc;
    shift[c] = b[c] - mean * sc;
}

// ---------------- fused stats + raw transpose (VMEM-wide version) ----------------
__global__ __launch_bounds__(256) void stats_transpose_kernel(
    const float* __restrict__ in, short* __restrict__ Bt,
    float* __restrict__ sum, float* __restrict__ sq, int C, int SP) {
    __shared__ short tile[64][66];
    __shared__ float rs[4][64], rq[4][64];
    int n = blockIdx.z;
    int ci0 = blockIdx.y * 64;
    int p0 = blockIdx.x * 64;
    int t = threadIdx.x;
    int tx = t & 63;
    int ty4 = t >> 6;  // 0..3

    // phase 1: float4 loads along p
    {
        int p4 = t & 15;
        int cib = t >> 4;
        int p = p0 + p4 * 4;
        bool pok = (p + 3) < SP;          // SP%4==0 -> all-or-none per float4
        #pragma unroll
        for (int it = 0; it < 4; it++) {
            int ci = cib + it * 16;
            float4 q;
            if (pok) q = *(const float4*)(in + ((size_t)n * C + ci0 + ci) * SP + p);
            else     q = make_float4(0.f, 0.f, 0.f, 0.f);
            tile[p4 * 4 + 0][ci] = f2bs(q.x);
            tile[p4 * 4 + 1][ci] = f2bs(q.y);
            tile[p4 * 4 + 2][ci] = f2bs(q.z);
            tile[p4 * 4 + 3][ci] = f2bs(q.w);
        }
    }
    __syncthreads();

    // phase 2a: int4 stores (8 shorts/lane)
    {
        int seg = t & 7;
        #pragma unroll
        for (int it = 0; it < 2; it++) {
            int pl = (t >> 3) + it * 32;
            int pw = p0 + pl;
            if (pw < SP) {
                short v[8];
                #pragma unroll
                for (int u = 0; u < 8; u++) v[u] = tile[pl][seg * 8 + u];
                *(int4*)(Bt + ((size_t)n * SP + pw) * C + ci0 + seg * 8) = *(int4*)v;
            }
        }
    }

    // phase 2b: per-channel stats from LDS
    float s = 0.f, s2 = 0.f;
    #pragma unroll
    for (int r = 0; r < 16; r++) {
        int pl = ty4 + r * 4;
        int pw = p0 + pl;
        if (pw < SP) {
            float v = bs2f(tile[pl][tx]);
            s += v; s2 += v * v;
        }
    }
    rs[ty4][tx] = s; rq[ty4][tx] = s2;
    __syncthreads();
    if (ty4 == 0) {
        float ts = rs[0][tx] + rs[1][tx] + rs[2][tx] + rs[3][tx];
        float tq = rq[0][tx] + rq[1][tx] + rq[2][tx] + rq[3][tx];
        atomicAdd(&sum[ci0 + tx], ts);
        atomicAdd(&sq[ci0 + tx], tq);
    }
}

// ---------------- affine transpose (bf16, VMEM-wide): h2 -> B3t ----------------
__global__ __launch_bounds__(256) void affine_transpose_bf16_kernel(
    const bf16* __restrict__ in, const float* __restrict__ scale,
    const float* __restrict__ shift, short* __restrict__ Bt,
    int C, int SP) {
    __shared__ short tile[64][66];
    int n = blockIdx.z;
    int ci0 = blockIdx.y * 64;
    int p0 = blockIdx.x * 64;
    int t = threadIdx.x;

    {
        int p4 = t & 15;
        int cib = t >> 4;
        int p = p0 + p4 * 4;
        bool pok = (p + 3) < SP;          // SP%4==0
        #pragma unroll
        for (int it = 0; it < 4; it++) {
            int ci = cib + it * 16;
            short v[4] = {0, 0, 0, 0};
            if (pok) *(int2*)v = *(const int2*)(in + ((size_t)n * C + ci0 + ci) * SP + p);
            float sc = scale[ci0 + ci], sh = shift[ci0 + ci];
            #pragma unroll
            for (int j = 0; j < 4; j++)
                tile[p4 * 4 + j][ci] = f2bs(bs2f(v[j]) * sc + sh);
        }
    }
    __syncthreads();

    {
        int seg = t & 7;
        #pragma unroll
        for (int it = 0; it < 2; it++) {
            int pl = (t >> 3) + it * 32;
            int pw = p0 + pl;
            if (pw < SP) {
                short v[8];
                #pragma unroll
                for (int u = 0; u < 8; u++) v[u] = tile[pl][seg * 8 + u];
                *(int4*)(Bt + ((size_t)n * SP + pw) * C + ci0 + seg * 8) = *(int4*)v;
            }
        }
    }
}

// ---------------- LDS-tiled im2col + affine for conv2 (3x3 s2 p1) ----------------
__global__ __launch_bounds__(256) void im2col_tiled_kernel(
    const bf16* __restrict__ h1, const float* __restrict__ scale,
    const float* __restrict__ shift, short* __restrict__ B2t) {
    __shared__ short tile[16][784];   // 25 KB
    int cb = blockIdx.x;              // 0..15 (16-channel slab)
    int n  = blockIdx.y;              // 0..63
    int ci0 = cb * 16;
    int t = threadIdx.x;

    for (int v = t; v < 16 * 98; v += 256) {
        int ci = v / 98;
        int i8 = (v - ci * 98) * 8;
        short tmp[8];
        *(int4*)tmp = *(const int4*)(h1 + ((size_t)n * 256 + ci0 + ci) * 784 + i8);
        float sc = scale[ci0 + ci], sh = shift[ci0 + ci];
        short ov[8];
        #pragma unroll
        for (int k = 0; k < 8; k++) ov[k] = f2bs(bs2f(tmp[k]) * sc + sh);
        *(int4*)&tile[ci][i8] = *(int4*)ov;
    }
    __syncthreads();

    for (int w = t; w < 196 * 18; w += 256) {
        int p = w / 18, seg = w - p * 18;
        int oh = p / 14, ow = p - oh * 14;
        int kbase = seg * 8;
        short vals[8];
        #pragma unroll
        for (int u = 0; u < 8; u++) {
            int kk = kbase + u;
            int ci_l = kk / 9;
            int rr = kk - ci_l * 9;
            int kh = rr / 3, kw = rr - kh * 3;
            int ih = 2 * oh - 1 + kh;
            int iw = 2 * ow - 1 + kw;
            vals[u] = ((unsigned)ih < 28u && (unsigned)iw < 28u)
                          ? tile[ci_l][ih * 28 + iw] : (short)0;
        }
        *(int4*)(B2t + ((size_t)(n * 196 + p)) * 2304 + ci0 * 9 + kbase) = *(int4*)vals;
    }
}

// ---------------- MFMA GEMM (128x128 tile, BK=32, 4 waves, 4x4 16x16x32) ----------------
// VERBATIM round-3 kernel (benched 441.8us). The r4/r5 template restructure
// (rowB array + RA/RB loops) changed codegen (VGPR 88->76) and cost ~25-30us on
// EACH 128^2 GEMM (68 -> 92.7us measured) — do not re-templatize this body.
template <int SP, typename TOut, bool HAS_ALPHA, bool FUSE, bool HAS_BIAS, bool BREMAP>
__global__ __launch_bounds__(256) void gemm_kernel(
    const short* __restrict__ A, const short* __restrict__ Bt,
    const float* __restrict__ alpha, TOut* __restrict__ out,
    int M, int K,
    const bf16* __restrict__ scv, const float* __restrict__ fscale,
    const float* __restrict__ fshift, const float* __restrict__ bias) {
    __shared__ short As[128 * 32];
    __shared__ short Bs[128 * 32];
    int t = threadIdx.x;
    int c0 = blockIdx.x * 128;
    int m0 = blockIdx.y * 128;
    int w = t >> 6, l = t & 63;
    int wm = (w >> 1) * 64, wn = (w & 1) * 64;

    int r0 = t >> 2;
    int kg = (t & 3) * 8;

    // B row remap (hoisted: independent of k)
    size_t rowB0, rowB1;
    if (BREMAP) {
        int c = c0 + r0;
        int nn = c / 196, pp = c - nn * 196;
        int oh = pp / 14, ow = pp - oh * 14;
        rowB0 = (size_t)nn * 784 + oh * 56 + ow * 2;
        c += 64;
        nn = c / 196; pp = c - nn * 196;
        oh = pp / 14; ow = pp - oh * 14;
        rowB1 = (size_t)nn * 784 + oh * 56 + ow * 2;
    } else {
        rowB0 = c0 + r0;
        rowB1 = c0 + r0 + 64;
    }

    float4v acc[4][4];
    #pragma unroll
    for (int i = 0; i < 4; i++)
        #pragma unroll
        for (int j = 0; j < 4; j++) acc[i][j] = (float4v)0.f;

    int lm = (l >> 4);
    int lc = l & 15;

    for (int k0 = 0; k0 < K; k0 += 32) {
        int4 av0 = *(const int4*)(A + (size_t)(m0 + r0) * K + k0 + kg);
        int4 av1 = *(const int4*)(A + (size_t)(m0 + r0 + 64) * K + k0 + kg);
        int4 bv0 = *(const int4*)(Bt + rowB0 * K + k0 + kg);
        int4 bv1 = *(const int4*)(Bt + rowB1 * K + k0 + kg);
        __syncthreads();
        *(int4*)&As[r0 * 32 + kg] = av0;
        *(int4*)&As[(r0 + 64) * 32 + kg] = av1;
        *(int4*)&Bs[r0 * 32 + kg] = bv0;
        *(int4*)&Bs[(r0 + 64) * 32 + kg] = bv1;
        __syncthreads();

        short8 af[4], bfr[4];
        #pragma unroll
        for (int i = 0; i < 4; i++)
            af[i] = *(const short8*)&As[(wm + i * 16 + lc) * 32 + lm * 8];
        #pragma unroll
        for (int j = 0; j < 4; j++)
            bfr[j] = *(const short8*)&Bs[(wn + j * 16 + lc) * 32 + lm * 8];
        #pragma unroll
        for (int i = 0; i < 4; i++)
            #pragma unroll
            for (int j = 0; j < 4; j++)
                acc[i][j] = __builtin_amdgcn_mfma_f32_16x16x32_bf16(af[i], bfr[j], acc[i][j], 0, 0, 0);
    }

    #pragma unroll
    for (int i = 0; i < 4; i++) {
        #pragma unroll
        for (int r = 0; r < 4; r++) {
            int m = m0 + wm + i * 16 + lm * 4 + r;
            float a = HAS_ALPHA ? alpha[m] : 1.f;
            float bia = HAS_BIAS ? bias[m] : 0.f;
            float fsc = FUSE ? fscale[m] : 0.f;
            float fsh = FUSE ? fshift[m] : 0.f;
            #pragma unroll
            for (int j = 0; j < 4; j++) {
                int c = c0 + wn + j * 16 + lc;
                int n = c / SP;
                int p = c - n * SP;
                size_t idx = ((size_t)n * M + m) * SP + p;
                float v = acc[i][j][r];
                if (HAS_BIAS) v += bia;
                if (HAS_ALPHA) v *= a;
                if (FUSE) v += toF(scv[idx]) * fsc + fsh;
                stF(&out[idx], v);
            }
        }
    }
}

// ---------------- GEMM2-dedicated kernel: 64x64 tile ----------------
// Isolated occupancy fix for the skinny GEMM2 (M=256, K=2304): 128^2 tiling gives
// only 196 blocks on 256 CUs (8% occ, 68us, latency-bound — r3 counters). 64^2
// gives 784 blocks (~3/CU). Same loop structure as gemm_kernel, scalar loads.
__global__ __launch_bounds__(256) void gemm2_kernel(
    const short* __restrict__ A, const short* __restrict__ Bt,
    const float* __restrict__ alpha, bf16* __restrict__ out,
    int M, int K) {
    constexpr int SP = 196;
    __shared__ short As[64 * 32];
    __shared__ short Bs[64 * 32];
    int t = threadIdx.x;
    int c0 = blockIdx.x * 64;
    int m0 = blockIdx.y * 64;
    int w = t >> 6, l = t & 63;
    int wm = (w >> 1) * 32, wn = (w & 1) * 32;

    int r0 = t >> 2;          // 0..63
    int kg = (t & 3) * 8;     // 0,8,16,24

    float4v acc[2][2];
    #pragma unroll
    for (int i = 0; i < 2; i++)
        #pragma unroll
        for (int j = 0; j < 2; j++) acc[i][j] = (float4v)0.f;

    int lm = (l >> 4);
    int lc = l & 15;

    for (int k0 = 0; k0 < K; k0 += 32) {
        int4 av0 = *(const int4*)(A + (size_t)(m0 + r0) * K + k0 + kg);
        int4 bv0 = *(const int4*)(Bt + (size_t)(c0 + r0) * K + k0 + kg);
        __syncthreads();
        *(int4*)&As[r0 * 32 + kg] = av0;
        *(int4*)&Bs[r0 * 32 + kg] = bv0;
        __syncthreads();

        short8 af[2], bfr[2];
        #pragma unroll
        for (int i = 0; i < 2; i++)
            af[i] = *(const short8*)&As[(wm + i * 16 + lc) * 32 + lm * 8];
        #pragma unroll
        for (int j = 0; j < 2; j++)
            bfr[j] = *(const short8*)&Bs[(wn + j * 16 + lc) * 32 + lm * 8];
        #pragma unroll
        for (int i = 0; i < 2; i++)
            #pragma unroll
            for (int j = 0; j < 2; j++)
                acc[i][j] = __builtin_amdgcn_mfma_f32_16x16x32_bf16(af[i], bfr[j], acc[i][j], 0, 0, 0);
    }

    #pragma unroll
    for (int i = 0; i < 2; i++) {
        #pragma unroll
        for (int r = 0; r < 4; r++) {
            int m = m0 + wm + i * 16 + lm * 4 + r;
            float a = alpha[m];
            #pragma unroll
            for (int j = 0; j < 2; j++) {
                int c = c0 + wn + j * 16 + lc;
                int n = c / SP;
                int p = c - n * SP;
                out[((size_t)n * M + m) * SP + p] = __float2bfloat16(acc[i][j][r] * a);
            }
        }
    }
}

extern "C" void kernel_launch(void* const* d_in, const int* in_sizes, int n_in,
                              void* d_out, int out_size, void* d_ws, size_t ws_size,
                              hipStream_t stream) {
    const float* x      = (const float*)d_in[0];   // (64,512,28,28)
    const float* bn1_g  = (const float*)d_in[1];
    const float* bn1_b  = (const float*)d_in[2];
    const float* w1     = (const float*)d_in[3];   // (256,512,1,1)
    const float* bn2_g  = (const float*)d_in[4];
    const float* bn2_b  = (const float*)d_in[5];
    const float* w2     = (const float*)d_in[6];   // (256,256,3,3)
    const float* bn3_g  = (const float*)d_in[7];
    const float* bn3_b  = (const float*)d_in[8];
    const float* w3     = (const float*)d_in[9];   // (1024,256,1,1)
    const float* ds_w   = (const float*)d_in[10];  // (1024,512,1,1) NOT ternarized
    const float* dbn_g  = (const float*)d_in[11];
    const float* dbn_b  = (const float*)d_in[12];
    float* out = (float*)d_out;

    const int N = 64, C1 = 512, C2 = 256, C3 = 1024;
    const int SP1 = 784, SP2 = 196;
    const int NT1 = N * SP1;   // 50176
    const int NT2 = N * SP2;   // 12544

    // ---- workspace layout ----
    char* wsb = (char*)d_ws;
    size_t off = 0;
    auto alloc = [&](size_t bytes) { char* p = wsb + off; off += (bytes + 255) & ~(size_t)255; return p; };

    char* pool = alloc((size_t)NT2 * 2304 * 2);   // 57.8 MB: B1t (51.4) / B2t (57.8) / B3t (6.4) time-share
    short* B1t = (short*)pool;                    // raw bf16(x)^T; live until GEMM4
    short* B2t = (short*)pool;                    // created by im2col AFTER GEMM4
    short* B3t = (short*)pool;                    // created after B2t is dead
    bf16*  sc  = (bf16*)alloc((size_t)N * C3 * SP2 * 2);  // 25.7 MB, own region (lives across im2col)

    bf16* h1 = (bf16*)alloc((size_t)N * C2 * SP1 * 2);
    bf16* h2 = (bf16*)alloc((size_t)N * C2 * SP2 * 2);
    short* w1t  = (short*)alloc((size_t)C2 * C1 * 2);
    short* w1f  = (short*)alloc((size_t)C2 * C1 * 2);   // scale-folded w1
    short* w2t  = (short*)alloc((size_t)C2 * C2 * 9 * 2);
    short* w3t  = (short*)alloc((size_t)C3 * C2 * 2);
    short* dswb = (short*)alloc((size_t)C3 * C1 * 2);
    float* alpha1 = (float*)alloc(C2 * 4);
    float* alpha2 = (float*)alloc(C2 * 4);
    float* alpha3 = (float*)alloc(C3 * 4);
    float* bias1  = (float*)alloc(C2 * 4);
    float* scale1 = (float*)alloc(C1 * 4);
    float* shift1 = (float*)alloc(C1 * 4);
    float* scale2 = (float*)alloc(C2 * 4);
    float* shift2 = (float*)alloc(C2 * 4);
    float* scale3 = (float*)alloc(C2 * 4);
    float* shift3 = (float*)alloc(C2 * 4);
    float* scaled = (float*)alloc(C3 * 4);
    float* shiftd = (float*)alloc(C3 * 4);
    float* acc_base = (float*)alloc((size_t)(C1 + C2 + C2 + C3) * 2 * 4);
    float* sum1 = acc_base;            float* sq1 = sum1 + C1;
    float* sum2 = sq1 + C1;            float* sq2 = sum2 + C2;
    float* sum3 = sq2 + C2;            float* sq3 = sum3 + C2;
    float* sumd = sq3 + C2;            float* sqd = sumd + C3;
    (void)ws_size; (void)in_sizes; (void)n_in; (void)out_size;

    // 0) zero BN accumulators
    hipMemsetAsync(acc_base, 0, (size_t)(C1 + C2 + C2 + C3) * 2 * 4, stream);

    // 1) weights
    ternarize_kernel<<<C2, 256, 0, stream>>>(w1, w1t, alpha1, C1);
    ternarize_kernel<<<C2, 256, 0, stream>>>(w2, w2t, alpha2, C2 * 9);
    ternarize_kernel<<<C3, 256, 0, stream>>>(w3, w3t, alpha3, C2);
    f2bf_kernel<<<(C3 * C1 + 255) / 256, 256, 0, stream>>>(ds_w, dswb, C3 * C1);

    // 2) single pass over x: B1t = raw bf16(x)^T + bn1 stats; then finalize + fold into w1
    {
        dim3 grid((SP1 + 63) / 64, C1 / 64, N);
        stats_transpose_kernel<<<grid, 256, 0, stream>>>(x, B1t, sum1, sq1, C1, SP1);
    }
    bn_finalize_kernel<<<(C1 + 255) / 256, 256, 0, stream>>>(sum1, sq1, bn1_g, bn1_b,
                                                             scale1, shift1, C1, (float)(N * SP1));
    foldbias_kernel<<<C2, 256, 0, stream>>>(w1t, scale1, shift1, w1f, bias1, C1);

    // 3) GEMM1: h1 = alpha1 * (w1f . B1t^T + bias1)   M=256 K=512 SP=784
    gemm_kernel<784, bf16, true, false, true, false><<<dim3(NT1 / 128, C2 / 128), 256, 0, stream>>>(
        w1f, B1t, alpha1, h1, C2, C1, nullptr, nullptr, nullptr, bias1);

    // 4) shortcut GEMM4 straight from raw B1t (stride-2 row remap): sc = dswb . B1t_s2^T
    //    M=1024 K=512 SP=196 — must run BEFORE im2col overwrites the pool
    gemm_kernel<196, bf16, false, false, false, true><<<dim3(NT2 / 128, C3 / 128), 256, 0, stream>>>(
        dswb, B1t, nullptr, sc, C3, C1, nullptr, nullptr, nullptr, nullptr);

    // 5) ds bn stats on sc
    bn_sum_kernel<bf16, 4><<<dim3(C3, 4), 256, 0, stream>>>(sc, sumd, sqd, C3, SP2, N, 4);
    bn_finalize_kernel<<<(C3 + 255) / 256, 256, 0, stream>>>(sumd, sqd, dbn_g, dbn_b,
                                                             scaled, shiftd, C3, (float)(N * SP2));

    // 6) bn2 stats + LDS-tiled im2col (B2t overwrites pool — B1t dead now)
    bn_sum_kernel<bf16, 8><<<dim3(C2, 8), 256, 0, stream>>>(h1, sum2, sq2, C2, SP1, N, 8);
    bn_finalize_kernel<<<(C2 + 255) / 256, 256, 0, stream>>>(sum2, sq2, bn2_g, bn2_b,
                                                             scale2, shift2, C2, (float)(N * SP1));
    im2col_tiled_kernel<<<dim3(16, 64), 256, 0, stream>>>(h1, scale2, shift2, B2t);

    // 7) GEMM2 (dedicated 64x64 kernel): h2 = alpha2 * (w2t . B2t^T)  M=256 K=2304
    //    784 blocks (~3/CU) vs 196 at 128^2 — grid-starvation fix, isolated from
    //    the verified 128^2 kernel used by GEMM1/3/4.
    gemm2_kernel<<<dim3(NT2 / 64, C2 / 64), 256, 0, stream>>>(
        w2t, B2t, alpha2, h2, C2, C2 * 9);

    // 8) bn3 stats + B3t = bn3(h2)^T (vectorized transpose)
    bn_sum_kernel<bf16, 4><<<dim3(C2, 4), 256, 0, stream>>>(h2, sum3, sq3, C2, SP2, N, 4);
    bn_finalize_kernel<<<(C2 + 255) / 256, 256, 0, stream>>>(sum3, sq3, bn3_g, bn3_b,
                                                             scale3, shift3, C2, (float)(N * SP2));
    {
        dim3 grid((SP2 + 63) / 64, C2 / 64, N);
        affine_transpose_bf16_kernel<<<grid, 256, 0, stream>>>(
            h2, scale3, shift3, B3t, C2, SP2);
    }

    // 9) GEMM3 with fused residual: out = alpha3*(w3t . B3t^T) + sc*scaled + shiftd
    gemm_kernel<196, float, true, true, false, false><<<dim3(NT2 / 128, C3 / 128), 256, 0, stream>>>(
        w3t, B3t, alpha3, out, C3, C2, sc, scaled, shiftd, nullptr);
}

// Round 8
// 428.517 us; speedup vs baseline: 1.2947x; 1.0167x over previous
//
#include <hip/hip_runtime.h>
#include <hip/hip_bf16.h>
#include <math.h>

#define EPS 1e-5f

typedef __hip_bfloat16 bf16;
typedef short short8 __attribute__((ext_vector_type(8)));
typedef float float4v __attribute__((ext_vector_type(4)));

__device__ __forceinline__ float toF(float v) { return v; }
__device__ __forceinline__ float toF(bf16 v) { return __bfloat162float(v); }
__device__ __forceinline__ void stF(float* p, float v) { *p = v; }
__device__ __forceinline__ void stF(bf16* p, float v) { *p = __float2bfloat16(v); }
__device__ __forceinline__ short f2bs(float v) {
    bf16 b = __float2bfloat16(v);
    return *reinterpret_cast<short*>(&b);
}
__device__ __forceinline__ float bs2f(short s) {
    unsigned u = ((unsigned)(unsigned short)s) << 16;
    return __uint_as_float(u);
}

// direct global->LDS DMA, 16B per lane. LDS dest: wave-uniform base + lane*16.
// Our staging layout (thread t -> LDS bytes [16t,16t+16)) matches exactly.
__device__ __forceinline__ void gload_lds16(const short* g, short* l) {
    __builtin_amdgcn_global_load_lds(
        (const __attribute__((address_space(1))) unsigned int*)g,
        (__attribute__((address_space(3))) unsigned int*)l, 16, 0, 0);
}

// ---------------- block reduction (blockDim.x == 256) ----------------
__device__ __forceinline__ float block_reduce_sum(float v) {
    __shared__ float s[256];
    int t = threadIdx.x;
    s[t] = v;
    __syncthreads();
    #pragma unroll
    for (int st = 128; st > 0; st >>= 1) {
        if (t < st) s[t] += s[t + st];
        __syncthreads();
    }
    float r = s[0];
    __syncthreads();
    return r;
}

// ---------------- ternarize -> bf16 {-1,0,+1} + fp32 alpha ----------------
__global__ void ternarize_kernel(const float* __restrict__ w, short* __restrict__ wt,
                                 float* __restrict__ alpha, int K) {
    int f = blockIdx.x;
    const float* wf = w + (size_t)f * K;
    short* wtf = wt + (size_t)f * K;

    float s = 0.f;
    for (int i = threadIdx.x; i < K; i += blockDim.x) s += fabsf(wf[i]);
    float total = block_reduce_sum(s);
    float delta = 0.7f * total / (float)K;

    float sm = 0.f, cm = 0.f;
    for (int i = threadIdx.x; i < K; i += blockDim.x) {
        float a = fabsf(wf[i]);
        if (a > delta) { sm += a; cm += 1.f; }
    }
    sm = block_reduce_sum(sm);
    cm = block_reduce_sum(cm);
    if (threadIdx.x == 0) alpha[f] = sm / (cm + 1e-8f);

    for (int i = threadIdx.x; i < K; i += blockDim.x) {
        float v = wf[i];
        float a = fabsf(v);
        wtf[i] = (a > delta) ? ((v > 0.f) ? (short)0x3F80 : (short)0xBF80) : (short)0;
    }
}

// ---------------- fold bn1 scale into w1t + compute bias1 = w1t . shift1 ----------------
__global__ void foldbias_kernel(const short* __restrict__ wt, const float* __restrict__ scale,
                                const float* __restrict__ shift, short* __restrict__ wf,
                                float* __restrict__ bias, int K) {
    int f = blockIdx.x;
    float s = 0.f;
    for (int k = threadIdx.x; k < K; k += blockDim.x) {
        float tv = bs2f(wt[(size_t)f * K + k]);
        wf[(size_t)f * K + k] = f2bs(tv * scale[k]);
        s += tv * shift[k];
    }
    s = block_reduce_sum(s);
    if (threadIdx.x == 0) bias[f] = s;
}

// ---------------- fp32 -> bf16 cast ----------------
__global__ void f2bf_kernel(const float* __restrict__ in, short* __restrict__ out, int n) {
    int i = blockIdx.x * blockDim.x + threadIdx.x;
    if (i < n) out[i] = f2bs(in[i]);
}

// ---------------- BN stats phase A: vectorized partial sums + atomics ----------------
template <typename T, int VEC>
__global__ __launch_bounds__(256) void bn_sum_kernel(
    const T* __restrict__ src, float* __restrict__ sum, float* __restrict__ sq,
    int C, int spatial, int N, int splits) {
    int c = blockIdx.x;
    int vpc = spatial / VEC;          // vectors per (n,c) chunk
    int total = N * vpc;
    float s = 0.f, s2 = 0.f;
    for (int v = blockIdx.y * 256 + threadIdx.x; v < total; v += splits * 256) {
        int n = v / vpc;
        int i = v - n * vpc;
        const T* p = src + ((size_t)n * C + c) * spatial + i * VEC;
        float vals[VEC];
        if (sizeof(T) == 4) {
            float4 q = *(const float4*)p;
            vals[0] = q.x; vals[1] = q.y; vals[2] = q.z; vals[3] = q.w;
        } else {
            short tmp[VEC];
            if (VEC == 8) *(int4*)tmp = *(const int4*)p;
            else          *(int2*)tmp = *(const int2*)p;
            #pragma unroll
            for (int k = 0; k < VEC; k++) vals[k] = bs2f(tmp[k]);
        }
        #pragma unroll
        for (int k = 0; k < VEC; k++) { s += vals[k]; s2 += vals[k] * vals[k]; }
    }
    s = block_reduce_sum(s);
    s2 = block_reduce_sum(s2);
    if (threadIdx.x == 0) {
        atomicAdd(&sum[c], s);
        atomicAdd(&sq[c], s2);
    }
}

// ---------------- BN stats phase B: finalize scale/shift ----------------
__global__ void bn_finalize_kernel(const float* __restrict__ sum, const float* __restrict__ sq,
                                   const float* __restrict__ g, const float* __restrict__ b,
                                   float* __restrict__ scale, float* __restrict__ shift,
                                   int C, float cnt) {
    int c = blockIdx.x * blockDim.x + threadIdx.x;
    if (c >= C) return;
    float mean = sum[c] / cnt;
    float var = fmaxf(sq[c] / cnt - mean * mean, 0.f);
    float r = rsqrtf(var + EPS);
    float sc = g[c] * r;
    scale[c] = sc;
    shift[c] = b[c] - mean * sc;
}

// ---------------- fused stats + raw transpose (VMEM-wide version) ----------------
__global__ __launch_bounds__(256) void stats_transpose_kernel(
    const float* __restrict__ in, short* __restrict__ Bt,
    float* __restrict__ sum, float* __restrict__ sq, int C, int SP) {
    __shared__ short tile[64][66];
    __shared__ float rs[4][64], rq[4][64];
    int n = blockIdx.z;
    int ci0 = blockIdx.y * 64;
    int p0 = blockIdx.x * 64;
    int t = threadIdx.x;
    int tx = t & 63;
    int ty4 = t >> 6;  // 0..3

    // phase 1: float4 loads along p
    {
        int p4 = t & 15;
        int cib = t >> 4;
        int p = p0 + p4 * 4;
        bool pok = (p + 3) < SP;          // SP%4==0 -> all-or-none per float4
        #pragma unroll
        for (int it = 0; it < 4; it++) {
            int ci = cib + it * 16;
            float4 q;
            if (pok) q = *(const float4*)(in + ((size_t)n * C + ci0 + ci) * SP + p);
            else     q = make_float4(0.f, 0.f, 0.f, 0.f);
            tile[p4 * 4 + 0][ci] = f2bs(q.x);
            tile[p4 * 4 + 1][ci] = f2bs(q.y);
            tile[p4 * 4 + 2][ci] = f2bs(q.z);
            tile[p4 * 4 + 3][ci] = f2bs(q.w);
        }
    }
    __syncthreads();

    // phase 2a: int4 stores (8 shorts/lane)
    {
        int seg = t & 7;
        #pragma unroll
        for (int it = 0; it < 2; it++) {
            int pl = (t >> 3) + it * 32;
            int pw = p0 + pl;
            if (pw < SP) {
                short v[8];
                #pragma unroll
                for (int u = 0; u < 8; u++) v[u] = tile[pl][seg * 8 + u];
                *(int4*)(Bt + ((size_t)n * SP + pw) * C + ci0 + seg * 8) = *(int4*)v;
            }
        }
    }

    // phase 2b: per-channel stats from LDS
    float s = 0.f, s2 = 0.f;
    #pragma unroll
    for (int r = 0; r < 16; r++) {
        int pl = ty4 + r * 4;
        int pw = p0 + pl;
        if (pw < SP) {
            float v = bs2f(tile[pl][tx]);
            s += v; s2 += v * v;
        }
    }
    rs[ty4][tx] = s; rq[ty4][tx] = s2;
    __syncthreads();
    if (ty4 == 0) {
        float ts = rs[0][tx] + rs[1][tx] + rs[2][tx] + rs[3][tx];
        float tq = rq[0][tx] + rq[1][tx] + rq[2][tx] + rq[3][tx];
        atomicAdd(&sum[ci0 + tx], ts);
        atomicAdd(&sq[ci0 + tx], tq);
    }
}

// ---------------- affine transpose (bf16, VMEM-wide): h2 -> B3t ----------------
__global__ __launch_bounds__(256) void affine_transpose_bf16_kernel(
    const bf16* __restrict__ in, const float* __restrict__ scale,
    const float* __restrict__ shift, short* __restrict__ Bt,
    int C, int SP) {
    __shared__ short tile[64][66];
    int n = blockIdx.z;
    int ci0 = blockIdx.y * 64;
    int p0 = blockIdx.x * 64;
    int t = threadIdx.x;

    {
        int p4 = t & 15;
        int cib = t >> 4;
        int p = p0 + p4 * 4;
        bool pok = (p + 3) < SP;          // SP%4==0
        #pragma unroll
        for (int it = 0; it < 4; it++) {
            int ci = cib + it * 16;
            short v[4] = {0, 0, 0, 0};
            if (pok) *(int2*)v = *(const int2*)(in + ((size_t)n * C + ci0 + ci) * SP + p);
            float sc = scale[ci0 + ci], sh = shift[ci0 + ci];
            #pragma unroll
            for (int j = 0; j < 4; j++)
                tile[p4 * 4 + j][ci] = f2bs(bs2f(v[j]) * sc + sh);
        }
    }
    __syncthreads();

    {
        int seg = t & 7;
        #pragma unroll
        for (int it = 0; it < 2; it++) {
            int pl = (t >> 3) + it * 32;
            int pw = p0 + pl;
            if (pw < SP) {
                short v[8];
                #pragma unroll
                for (int u = 0; u < 8; u++) v[u] = tile[pl][seg * 8 + u];
                *(int4*)(Bt + ((size_t)n * SP + pw) * C + ci0 + seg * 8) = *(int4*)v;
            }
        }
    }
}

// ---------------- LDS-tiled im2col + affine for conv2 (3x3 s2 p1) ----------------
__global__ __launch_bounds__(256) void im2col_tiled_kernel(
    const bf16* __restrict__ h1, const float* __restrict__ scale,
    const float* __restrict__ shift, short* __restrict__ B2t) {
    __shared__ short tile[16][784];   // 25 KB
    int cb = blockIdx.x;              // 0..15 (16-channel slab)
    int n  = blockIdx.y;              // 0..63
    int ci0 = cb * 16;
    int t = threadIdx.x;

    for (int v = t; v < 16 * 98; v += 256) {
        int ci = v / 98;
        int i8 = (v - ci * 98) * 8;
        short tmp[8];
        *(int4*)tmp = *(const int4*)(h1 + ((size_t)n * 256 + ci0 + ci) * 784 + i8);
        float sc = scale[ci0 + ci], sh = shift[ci0 + ci];
        short ov[8];
        #pragma unroll
        for (int k = 0; k < 8; k++) ov[k] = f2bs(bs2f(tmp[k]) * sc + sh);
        *(int4*)&tile[ci][i8] = *(int4*)ov;
    }
    __syncthreads();

    for (int w = t; w < 196 * 18; w += 256) {
        int p = w / 18, seg = w - p * 18;
        int oh = p / 14, ow = p - oh * 14;
        int kbase = seg * 8;
        short vals[8];
        #pragma unroll
        for (int u = 0; u < 8; u++) {
            int kk = kbase + u;
            int ci_l = kk / 9;
            int rr = kk - ci_l * 9;
            int kh = rr / 3, kw = rr - kh * 3;
            int ih = 2 * oh - 1 + kh;
            int iw = 2 * ow - 1 + kw;
            vals[u] = ((unsigned)ih < 28u && (unsigned)iw < 28u)
                          ? tile[ci_l][ih * 28 + iw] : (short)0;
        }
        *(int4*)(B2t + ((size_t)(n * 196 + p)) * 2304 + ci0 * 9 + kbase) = *(int4*)vals;
    }
}

// ---------------- MFMA GEMM (128x128 tile, BK=32, 4 waves, 4x4 16x16x32) ----------------
// Round-6 body (435.7us verified) with ONE change: staging via global_load_lds
// width=16 DMA instead of reg round-trip (int4 load + ds_write). Guide §5
// Common-mistake #1: +67% measured on this structure. Thread t's LDS slot is
// bytes [16t,16t+16) — exactly the DMA's wave-uniform-base + lane*16 layout.
// Everything else (fragments, epilogue, rowB scalars) verbatim.
template <int SP, typename TOut, bool HAS_ALPHA, bool FUSE, bool HAS_BIAS, bool BREMAP>
__global__ __launch_bounds__(256) void gemm_kernel(
    const short* __restrict__ A, const short* __restrict__ Bt,
    const float* __restrict__ alpha, TOut* __restrict__ out,
    int M, int K,
    const bf16* __restrict__ scv, const float* __restrict__ fscale,
    const float* __restrict__ fshift, const float* __restrict__ bias) {
    __shared__ short As[128 * 32];
    __shared__ short Bs[128 * 32];
    int t = threadIdx.x;
    int c0 = blockIdx.x * 128;
    int m0 = blockIdx.y * 128;
    int w = t >> 6, l = t & 63;
    int wm = (w >> 1) * 64, wn = (w & 1) * 64;

    int r0 = t >> 2;
    int kg = (t & 3) * 8;
    int wbase = w * 512;     // wave's LDS chunk start (shorts): lane l lands at +l*8

    // B row remap (hoisted: independent of k)
    size_t rowB0, rowB1;
    if (BREMAP) {
        int c = c0 + r0;
        int nn = c / 196, pp = c - nn * 196;
        int oh = pp / 14, ow = pp - oh * 14;
        rowB0 = (size_t)nn * 784 + oh * 56 + ow * 2;
        c += 64;
        nn = c / 196; pp = c - nn * 196;
        oh = pp / 14; ow = pp - oh * 14;
        rowB1 = (size_t)nn * 784 + oh * 56 + ow * 2;
    } else {
        rowB0 = c0 + r0;
        rowB1 = c0 + r0 + 64;
    }

    float4v acc[4][4];
    #pragma unroll
    for (int i = 0; i < 4; i++)
        #pragma unroll
        for (int j = 0; j < 4; j++) acc[i][j] = (float4v)0.f;

    int lm = (l >> 4);
    int lc = l & 15;

    for (int k0 = 0; k0 < K; k0 += 32) {
        // direct global->LDS DMA (per-lane global src, wave-uniform LDS base)
        gload_lds16(A + (size_t)(m0 + r0) * K + k0 + kg,      &As[wbase]);
        gload_lds16(A + (size_t)(m0 + r0 + 64) * K + k0 + kg, &As[2048 + wbase]);
        gload_lds16(Bt + rowB0 * K + k0 + kg,                 &Bs[wbase]);
        gload_lds16(Bt + rowB1 * K + k0 + kg,                 &Bs[2048 + wbase]);
        __syncthreads();   // drains vmcnt (DMA landed) + barrier

        short8 af[4], bfr[4];
        #pragma unroll
        for (int i = 0; i < 4; i++)
            af[i] = *(const short8*)&As[(wm + i * 16 + lc) * 32 + lm * 8];
        #pragma unroll
        for (int j = 0; j < 4; j++)
            bfr[j] = *(const short8*)&Bs[(wn + j * 16 + lc) * 32 + lm * 8];
        #pragma unroll
        for (int i = 0; i < 4; i++)
            #pragma unroll
            for (int j = 0; j < 4; j++)
                acc[i][j] = __builtin_amdgcn_mfma_f32_16x16x32_bf16(af[i], bfr[j], acc[i][j], 0, 0, 0);
        __syncthreads();   // all reads done before next iter's DMA writes
    }

    #pragma unroll
    for (int i = 0; i < 4; i++) {
        #pragma unroll
        for (int r = 0; r < 4; r++) {
            int m = m0 + wm + i * 16 + lm * 4 + r;
            float a = HAS_ALPHA ? alpha[m] : 1.f;
            float bia = HAS_BIAS ? bias[m] : 0.f;
            float fsc = FUSE ? fscale[m] : 0.f;
            float fsh = FUSE ? fshift[m] : 0.f;
            #pragma unroll
            for (int j = 0; j < 4; j++) {
                int c = c0 + wn + j * 16 + lc;
                int n = c / SP;
                int p = c - n * SP;
                size_t idx = ((size_t)n * M + m) * SP + p;
                float v = acc[i][j][r];
                if (HAS_BIAS) v += bia;
                if (HAS_ALPHA) v *= a;
                if (FUSE) v += toF(scv[idx]) * fsc + fsh;
                stF(&out[idx], v);
            }
        }
    }
}

// ---------------- GEMM2-dedicated kernel: 64x64 tile (784 blocks) ----------------
// Same global_load_lds staging change as gemm_kernel.
__global__ __launch_bounds__(256) void gemm2_kernel(
    const short* __restrict__ A, const short* __restrict__ Bt,
    const float* __restrict__ alpha, bf16* __restrict__ out,
    int M, int K) {
    constexpr int SP = 196;
    __shared__ short As[64 * 32];
    __shared__ short Bs[64 * 32];
    int t = threadIdx.x;
    int c0 = blockIdx.x * 64;
    int m0 = blockIdx.y * 64;
    int w = t >> 6, l = t & 63;
    int wm = (w >> 1) * 32, wn = (w & 1) * 32;

    int r0 = t >> 2;          // 0..63
    int kg = (t & 3) * 8;     // 0,8,16,24
    int wbase = w * 512;

    float4v acc[2][2];
    #pragma unroll
    for (int i = 0; i < 2; i++)
        #pragma unroll
        for (int j = 0; j < 2; j++) acc[i][j] = (float4v)0.f;

    int lm = (l >> 4);
    int lc = l & 15;

    for (int k0 = 0; k0 < K; k0 += 32) {
        gload_lds16(A + (size_t)(m0 + r0) * K + k0 + kg,  &As[wbase]);
        gload_lds16(Bt + (size_t)(c0 + r0) * K + k0 + kg, &Bs[wbase]);
        __syncthreads();

        short8 af[2], bfr[2];
        #pragma unroll
        for (int i = 0; i < 2; i++)
            af[i] = *(const short8*)&As[(wm + i * 16 + lc) * 32 + lm * 8];
        #pragma unroll
        for (int j = 0; j < 2; j++)
            bfr[j] = *(const short8*)&Bs[(wn + j * 16 + lc) * 32 + lm * 8];
        #pragma unroll
        for (int i = 0; i < 2; i++)
            #pragma unroll
            for (int j = 0; j < 2; j++)
                acc[i][j] = __builtin_amdgcn_mfma_f32_16x16x32_bf16(af[i], bfr[j], acc[i][j], 0, 0, 0);
        __syncthreads();
    }

    #pragma unroll
    for (int i = 0; i < 2; i++) {
        #pragma unroll
        for (int r = 0; r < 4; r++) {
            int m = m0 + wm + i * 16 + lm * 4 + r;
            float a = alpha[m];
            #pragma unroll
            for (int j = 0; j < 2; j++) {
                int c = c0 + wn + j * 16 + lc;
                int n = c / SP;
                int p = c - n * SP;
                out[((size_t)n * M + m) * SP + p] = __float2bfloat16(acc[i][j][r] * a);
            }
        }
    }
}

extern "C" void kernel_launch(void* const* d_in, const int* in_sizes, int n_in,
                              void* d_out, int out_size, void* d_ws, size_t ws_size,
                              hipStream_t stream) {
    const float* x      = (const float*)d_in[0];   // (64,512,28,28)
    const float* bn1_g  = (const float*)d_in[1];
    const float* bn1_b  = (const float*)d_in[2];
    const float* w1     = (const float*)d_in[3];   // (256,512,1,1)
    const float* bn2_g  = (const float*)d_in[4];
    const float* bn2_b  = (const float*)d_in[5];
    const float* w2     = (const float*)d_in[6];   // (256,256,3,3)
    const float* bn3_g  = (const float*)d_in[7];
    const float* bn3_b  = (const float*)d_in[8];
    const float* w3     = (const float*)d_in[9];   // (1024,256,1,1)
    const float* ds_w   = (const float*)d_in[10];  // (1024,512,1,1) NOT ternarized
    const float* dbn_g  = (const float*)d_in[11];
    const float* dbn_b  = (const float*)d_in[12];
    float* out = (float*)d_out;

    const int N = 64, C1 = 512, C2 = 256, C3 = 1024;
    const int SP1 = 784, SP2 = 196;
    const int NT1 = N * SP1;   // 50176
    const int NT2 = N * SP2;   // 12544

    // ---- workspace layout ----
    char* wsb = (char*)d_ws;
    size_t off = 0;
    auto alloc = [&](size_t bytes) { char* p = wsb + off; off += (bytes + 255) & ~(size_t)255; return p; };

    char* pool = alloc((size_t)NT2 * 2304 * 2);   // 57.8 MB: B1t (51.4) / B2t (57.8) / B3t (6.4) time-share
    short* B1t = (short*)pool;                    // raw bf16(x)^T; live until GEMM4
    short* B2t = (short*)pool;                    // created by im2col AFTER GEMM4
    short* B3t = (short*)pool;                    // created after B2t is dead
    bf16*  sc  = (bf16*)alloc((size_t)N * C3 * SP2 * 2);  // 25.7 MB, own region (lives across im2col)

    bf16* h1 = (bf16*)alloc((size_t)N * C2 * SP1 * 2);
    bf16* h2 = (bf16*)alloc((size_t)N * C2 * SP2 * 2);
    short* w1t  = (short*)alloc((size_t)C2 * C1 * 2);
    short* w1f  = (short*)alloc((size_t)C2 * C1 * 2);   // scale-folded w1
    short* w2t  = (short*)alloc((size_t)C2 * C2 * 9 * 2);
    short* w3t  = (short*)alloc((size_t)C3 * C2 * 2);
    short* dswb = (short*)alloc((size_t)C3 * C1 * 2);
    float* alpha1 = (float*)alloc(C2 * 4);
    float* alpha2 = (float*)alloc(C2 * 4);
    float* alpha3 = (float*)alloc(C3 * 4);
    float* bias1  = (float*)alloc(C2 * 4);
    float* scale1 = (float*)alloc(C1 * 4);
    float* shift1 = (float*)alloc(C1 * 4);
    float* scale2 = (float*)alloc(C2 * 4);
    float* shift2 = (float*)alloc(C2 * 4);
    float* scale3 = (float*)alloc(C2 * 4);
    float* shift3 = (float*)alloc(C2 * 4);
    float* scaled = (float*)alloc(C3 * 4);
    float* shiftd = (float*)alloc(C3 * 4);
    float* acc_base = (float*)alloc((size_t)(C1 + C2 + C2 + C3) * 2 * 4);
    float* sum1 = acc_base;            float* sq1 = sum1 + C1;
    float* sum2 = sq1 + C1;            float* sq2 = sum2 + C2;
    float* sum3 = sq2 + C2;            float* sq3 = sum3 + C2;
    float* sumd = sq3 + C2;            float* sqd = sumd + C3;
    (void)ws_size; (void)in_sizes; (void)n_in; (void)out_size;

    // 0) zero BN accumulators
    hipMemsetAsync(acc_base, 0, (size_t)(C1 + C2 + C2 + C3) * 2 * 4, stream);

    // 1) weights
    ternarize_kernel<<<C2, 256, 0, stream>>>(w1, w1t, alpha1, C1);
    ternarize_kernel<<<C2, 256, 0, stream>>>(w2, w2t, alpha2, C2 * 9);
    ternarize_kernel<<<C3, 256, 0, stream>>>(w3, w3t, alpha3, C2);
    f2bf_kernel<<<(C3 * C1 + 255) / 256, 256, 0, stream>>>(ds_w, dswb, C3 * C1);

    // 2) single pass over x: B1t = raw bf16(x)^T + bn1 stats; then finalize + fold into w1
    {
        dim3 grid((SP1 + 63) / 64, C1 / 64, N);
        stats_transpose_kernel<<<grid, 256, 0, stream>>>(x, B1t, sum1, sq1, C1, SP1);
    }
    bn_finalize_kernel<<<(C1 + 255) / 256, 256, 0, stream>>>(sum1, sq1, bn1_g, bn1_b,
                                                             scale1, shift1, C1, (float)(N * SP1));
    foldbias_kernel<<<C2, 256, 0, stream>>>(w1t, scale1, shift1, w1f, bias1, C1);

    // 3) GEMM1: h1 = alpha1 * (w1f . B1t^T + bias1)   M=256 K=512 SP=784
    gemm_kernel<784, bf16, true, false, true, false><<<dim3(NT1 / 128, C2 / 128), 256, 0, stream>>>(
        w1f, B1t, alpha1, h1, C2, C1, nullptr, nullptr, nullptr, bias1);

    // 4) shortcut GEMM4 straight from raw B1t (stride-2 row remap): sc = dswb . B1t_s2^T
    //    M=1024 K=512 SP=196 — must run BEFORE im2col overwrites the pool
    gemm_kernel<196, bf16, false, false, false, true><<<dim3(NT2 / 128, C3 / 128), 256, 0, stream>>>(
        dswb, B1t, nullptr, sc, C3, C1, nullptr, nullptr, nullptr, nullptr);

    // 5) ds bn stats on sc
    bn_sum_kernel<bf16, 4><<<dim3(C3, 4), 256, 0, stream>>>(sc, sumd, sqd, C3, SP2, N, 4);
    bn_finalize_kernel<<<(C3 + 255) / 256, 256, 0, stream>>>(sumd, sqd, dbn_g, dbn_b,
                                                             scaled, shiftd, C3, (float)(N * SP2));

    // 6) bn2 stats + LDS-tiled im2col (B2t overwrites pool — B1t dead now)
    bn_sum_kernel<bf16, 8><<<dim3(C2, 8), 256, 0, stream>>>(h1, sum2, sq2, C2, SP1, N, 8);
    bn_finalize_kernel<<<(C2 + 255) / 256, 256, 0, stream>>>(sum2, sq2, bn2_g, bn2_b,
                                                             scale2, shift2, C2, (float)(N * SP1));
    im2col_tiled_kernel<<<dim3(16, 64), 256, 0, stream>>>(h1, scale2, shift2, B2t);

    // 7) GEMM2 (dedicated 64x64 kernel): h2 = alpha2 * (w2t . B2t^T)  M=256 K=2304
    gemm2_kernel<<<dim3(NT2 / 64, C2 / 64), 256, 0, stream>>>(
        w2t, B2t, alpha2, h2, C2, C2 * 9);

    // 8) bn3 stats + B3t = bn3(h2)^T (vectorized transpose)
    bn_sum_kernel<bf16, 4><<<dim3(C2, 4), 256, 0, stream>>>(h2, sum3, sq3, C2, SP2, N, 4);
    bn_finalize_kernel<<<(C2 + 255) / 256, 256, 0, stream>>>(sum3, sq3, bn3_g, bn3_b,
                                                             scale3, shift3, C2, (float)(N * SP2));
    {
        dim3 grid((SP2 + 63) / 64, C2 / 64, N);
        affine_transpose_bf16_kernel<<<grid, 256, 0, stream>>>(
            h2, scale3, shift3, B3t, C2, SP2);
    }

    // 9) GEMM3 with fused residual: out = alpha3*(w3t . B3t^T) + sc*scaled + shiftd
    gemm_kernel<196, float, true, true, false, false><<<dim3(NT2 / 128, C3 / 128), 256, 0, stream>>>(
        w3t, B3t, alpha3, out, C3, C2, sc, scaled, shiftd, nullptr);
}